// Round 2
// baseline (32008.621 us; speedup 1.0000x reference)
//
#include <hip/hip_runtime.h>

typedef __attribute__((ext_vector_type(8))) short short8;
typedef __attribute__((ext_vector_type(4))) float f32x4;
typedef __attribute__((ext_vector_type(4))) unsigned short u16x4;
typedef unsigned short ushort;
typedef unsigned long long ull;

#define MFMA16(a,b,c) __builtin_amdgcn_mfma_f32_16x16x32_bf16((a),(b),(c),0,0,0)

static __device__ __forceinline__ float bf2f(ushort u){
  union { unsigned int i; float f; } z; z.i = ((unsigned int)u) << 16; return z.f;
}
static __device__ __forceinline__ ushort f2bf(float f){
  union { float f; unsigned int i; } z; z.f = f;
  unsigned int x = z.i;
  unsigned int r = (x + 0x7fffu + ((x >> 16) & 1u)) >> 16;   // RNE
  return (ushort)r;
}

// 16B coherence-point load (2x u64 agent atomics, bypass stale L1/L2)
static __device__ __forceinline__ short8 ld_hc16(const ushort* p){
  union { ull q[2]; short8 v; } u;
  u.q[0] = __hip_atomic_load((const ull*)p, __ATOMIC_RELAXED, __HIP_MEMORY_SCOPE_AGENT);
  u.q[1] = __hip_atomic_load((const ull*)(p + 4), __ATOMIC_RELAXED, __HIP_MEMORY_SCOPE_AGENT);
  return u.v;
}
// single bf16 from ring via aligned u32 agent atomic
static __device__ __forceinline__ float ld_ring_bf(const ushort* base, int idx){
  const unsigned int* p = (const unsigned int*)(base + (idx & ~1));
  unsigned int w = __hip_atomic_load(p, __ATOMIC_RELAXED, __HIP_MEMORY_SCOPE_AGENT);
  return bf2f((idx & 1) ? (ushort)(w >> 16) : (ushort)(w & 0xffffu));
}
// 2B / 8B write-through stores to coherence point
static __device__ __forceinline__ void st_hc2(ushort* p, ushort v){
  unsigned int vv = v;
  asm volatile("global_store_short %0, %1, off sc0 sc1" :: "v"(p), "v"(vv) : "memory");
}
static __device__ __forceinline__ void st_hc8(ushort* p, ull v){
  asm volatile("global_store_dwordx2 %0, %1, off sc0 sc1" :: "v"(p), "v"(v) : "memory");
}

// GRU gate math: updates hp to carried state (zoneout), returns hn (pre-zoneout)
static __device__ __forceinline__ void gru_gate(
    float mz, float mr, float mh, float xz, float xr, float xh,
    float& hp, float& hn)
{
  float z  = 1.f / (1.f + __expf(-(xz + mz)));
  float r  = 1.f / (1.f + __expf(-(xr + mr)));
  float axv = xh + r * mh;
  float hh = 1.f - 2.f / (1.f + __expf(2.f * axv));
  hn = z * hp + (1.f - z) * hh;
  float hcv = hn + 0.1f * (hp - hn);
  hp = hcv;
}

// ---------------------------------------------------------------------------
// fp32 -> bf16 convert, 4 elems/thread
// ---------------------------------------------------------------------------
__global__ __launch_bounds__(256) void cvt_k(
    const float* __restrict__ in, ushort* __restrict__ out, int n)
{
  int i = (blockIdx.x * 256 + threadIdx.x) * 4;
  if (i < n){
    float4 v = *(const float4*)(in + i);
    u16x4 o = { f2bf(v.x), f2bf(v.y), f2bf(v.z), f2bf(v.w) };
    *(u16x4*)(out + i) = o;
  }
}

// ---------------------------------------------------------------------------
// GEMM: C[M,N] = A[M,K](bf16) @ B[K,N](bf16) + bias[N](fp32).
// ---------------------------------------------------------------------------
template<int F32OUT>
__global__ __launch_bounds__(256) void gemm_bias_k(
    const ushort* __restrict__ A,
    const ushort* __restrict__ B,
    const float*  __restrict__ bias,
    void* __restrict__ Cv,
    int M, int N, int K)
{
  __shared__ __align__(16) ushort Blds[64 * 40];
  const int tid  = threadIdx.x;
  const int wid  = tid >> 6;
  const int lane = tid & 63;
  const int quad = lane >> 4;
  const int lc   = lane & 15;
  const int nb   = N >> 6;
  const int bn   = (blockIdx.x % nb) << 6;
  const int bm   = (blockIdx.x / nb) << 6;

  const int sk  = tid >> 3;
  const int scg = tid & 7;

  f32x4 acc[4] = {{0,0,0,0},{0,0,0,0},{0,0,0,0},{0,0,0,0}};
  const int arow = bm + wid * 16 + lc;
  const ushort* aptr = A + (size_t)arow * K + quad * 8;

  for (int k0 = 0; k0 < K; k0 += 32){
    short8 bv = *(const short8*)(B + (size_t)(k0 + sk) * N + bn + (scg << 3));
    #pragma unroll
    for (int i = 0; i < 8; ++i){
      int c = (scg << 3) + i;
      int p = c * 40 + (((sk >> 3) ^ (scg & 3)) << 3) + (sk & 7);
      Blds[p] = (ushort)bv[i];
    }
    __syncthreads();
    short8 av = *(const short8*)(aptr + k0);
    #pragma unroll
    for (int nt = 0; nt < 4; ++nt){
      int c2 = (nt << 4) + lc;
      int p  = c2 * 40 + ((quad ^ ((c2 >> 3) & 3)) << 3);
      short8 bfrag = *(const short8*)(Blds + p);
      acc[nt] = MFMA16(av, bfrag, acc[nt]);
    }
    __syncthreads();
  }
  #pragma unroll
  for (int nt = 0; nt < 4; ++nt){
    #pragma unroll
    for (int i = 0; i < 4; ++i){
      int m = bm + wid * 16 + quad * 4 + i;
      int n = bn + (nt << 4) + lc;
      float v = acc[nt][i] + bias[n];
      if (F32OUT) ((float*)Cv)[(size_t)m * N + n] = v;
      else        ((ushort*)Cv)[(size_t)m * N + n] = f2bf(v);
    }
  }
}

// ---------------------------------------------------------------------------
// MERGED 3-layer pipelined GRU recurrence: 32 WGs x 384 thr, ONE flag plane.
// WG g owns units [16g,16g+16) for ALL layers. At step t it computes
// layer0@t, layer1@(t-1), layer2@(t-2). All deps are "published at end of
// step t-1" -> single flag wait per step (1 load/lane poll). Flag-bounded
// drift <= 1 step -> ring depth 4 is safe, no back-pressure plane.
// Rings via sc0/sc1 coherence-point exchange (proven mechanics, unchanged).
// ---------------------------------------------------------------------------
#define NWG 32
#define RD 4
#define FSTEPS 1026

__global__ __launch_bounds__(384, 2) void rec1_k(
    const ushort* __restrict__ xw0,   // [32*1024,1536] bf16, row = b*1024+t
    const ushort* __restrict__ R0b,   // [512,1536]
    const ushort* __restrict__ Ksb,   // [512,1536]
    const ushort* __restrict__ Rsb,   // [512,1536]
    const float*  __restrict__ b0v,   // [2,1536]
    const float*  __restrict__ bsv,   // [2,1536]
    const float*  __restrict__ h00,
    const float*  __restrict__ h01,
    const float*  __restrict__ h02,
    const float*  __restrict__ av,    // [3]
    ushort* __restrict__ comb,        // [32*1024,512] bf16
    ushort* __restrict__ rings,
    int* __restrict__ flags)          // [FSTEPS][32]
{
  __shared__ float m_lds[3][3][32][17];                     // 19584 B
  __shared__ float x_lds[2][3][32][16];                     // 12288 B
  __shared__ float bias_l[144];                             // b0rec, bsrec, bsin
  __shared__ __align__(16) ushort ks_lds[3 * 16 * 64 * 8];  // 48 KB
  __shared__ __align__(16) ushort rs_lds[3 * 16 * 64 * 8];  // 48 KB

  const int tid  = threadIdx.x;
  const int wid  = tid >> 6;
  const int lane = tid & 63;
  const int quad = lane >> 4;
  const int lc   = lane & 15;
  const int g    = blockIdx.x;
  const int ug0  = g << 4;
  const int gate = wid % 3, mtile = wid / 3;
  const int col0 = (gate << 9) + ug0;

  // ring layout (ushort units), depth 4 each of [4][32][512]:
  ushort* h0ring    = rings;
  ushort* h1ring    = rings + 65536;
  ushort* h2ring    = rings + 131072;
  ushort* out0ring  = rings + 196608;
  ushort* pred0ring = rings + 262144;
  ushort* xw1ring   = rings + 327680;   // [4][32][512][4] = 262144 ushorts

  // ---- R0 slice into VGPR fragments ----
  short8 bfragR0[16];
  #pragma unroll
  for (int f = 0; f < 16; ++f){
    short8 v;
    #pragma unroll
    for (int j = 0; j < 8; ++j)
      v[j] = (short)R0b[(size_t)(f * 32 + quad * 8 + j) * 1536 + col0 + lc];
    bfragR0[f] = v;
  }
  // ---- Ks (mtile0 waves) and Rs (mtile1 waves) slices into LDS ----
  if (mtile == 0){
    #pragma unroll
    for (int f = 0; f < 16; ++f){
      short8 v;
      #pragma unroll
      for (int j = 0; j < 8; ++j)
        v[j] = (short)Ksb[(size_t)(f * 32 + quad * 8 + j) * 1536 + col0 + lc];
      *(short8*)(ks_lds + (((gate << 4) + f) << 9) + (lane << 3)) = v;
    }
  } else {
    #pragma unroll
    for (int f = 0; f < 16; ++f){
      short8 v;
      #pragma unroll
      for (int j = 0; j < 8; ++j)
        v[j] = (short)Rsb[(size_t)(f * 32 + quad * 8 + j) * 1536 + col0 + lc];
      *(short8*)(rs_lds + (((gate << 4) + f) << 9) + (lane << 3)) = v;
    }
  }
  // biases: [0:48) b0 rec, [48:96) bs rec, [96:144) bs input
  if (tid < 48)  bias_l[tid] = (b0v + 1536)[(tid >> 4) * 512 + ug0 + (tid & 15)];
  else if (tid < 96){ int j = tid - 48;  bias_l[tid] = (bsv + 1536)[(j >> 4) * 512 + ug0 + (j & 15)]; }
  else if (tid < 144){ int j = tid - 96; bias_l[tid] = bsv[(j >> 4) * 512 + ug0 + (j & 15)]; }

  const float a0 = av[0], a1 = av[1], a2 = av[2];

  const int  b0i  = tid >> 4;
  const int  u0   = tid & 15;
  const int  b1i  = (tid + 384) >> 4;
  const bool has1 = (tid < 128);
  const int  uu   = ug0 + u0;
  float hpA0 = h00[uu], hpB0 = hpA0;   // layer0 carried state
  float hpA1 = h01[uu], hpB1 = hpA1;   // layer1
  float hpA2 = h02[uu], hpB2 = hpA2;   // layer2

  // ---- layer0 xw prefetch for t=0 ----
  ushort xz0 = 0, xr0 = 0, xh0 = 0, xz1 = 0, xr1 = 0, xh1 = 0;
  {
    size_t r0_ = ((size_t)b0i * 1024) * 1536 + uu;
    xz0 = xw0[r0_]; xr0 = xw0[r0_ + 512]; xh0 = xw0[r0_ + 1024];
    if (has1){
      size_t r1_ = ((size_t)b1i * 1024) * 1536 + uu;
      xz1 = xw0[r1_]; xr1 = xw0[r1_ + 512]; xh1 = xw0[r1_ + 1024];
    }
  }
  __syncthreads();

  long budget = 40000000L;  // spin safety valve: degrade, don't hang
  for (int t = 0; t < FSTEPS; ++t){
    const bool L0on = (t < 1024);
    const bool L1on = (t >= 1) && (t < 1025);
    const bool L2on = (t >= 2);
    const int  tL1  = t - 1;
    const int  tL2  = t - 2;
    const int  slot0 = t & (RD - 1);
    const int  slot1 = tL1 & (RD - 1);
    const int  slot2 = tL2 & (RD - 1);

    // layer0: prefetch next xw (independent of flags)
    ushort nz0 = 0, nr0 = 0, nh0 = 0, nz1 = 0, nr1 = 0, nh1 = 0;
    if (t < 1023){
      size_t r0_ = ((size_t)b0i * 1024 + t + 1) * 1536 + uu;
      nz0 = xw0[r0_]; nr0 = xw0[r0_ + 512]; nh0 = xw0[r0_ + 1024];
      if (has1){
        size_t r1_ = ((size_t)b1i * 1024 + t + 1) * 1536 + uu;
        nz1 = xw0[r1_]; nr1 = xw0[r1_ + 512]; nh1 = xw0[r1_ + 1024];
      }
    }

    // ---- single-plane wait: all 32 WGs finished step t-1 ----
    if (t >= 1 && wid == 0){
      const int* fo = flags + (t - 1) * 32 + (lane & 31);
      while (budget > 0){
        bool ok = (__hip_atomic_load(fo, __ATOMIC_RELAXED, __HIP_MEMORY_SCOPE_AGENT) != 0);
        if (__ballot(ok) == ~0ull) break;
        --budget;
      }
    }
    __syncthreads();

    // ---- layer2 scalar ring loads (issued early, in flight with frag loads)
    float o_s0 = 0, p_s0 = 0, x1z0 = 0, x1r0 = 0, x1h0 = 0;
    float o_s1 = 0, p_s1 = 0, x1z1 = 0, x1r1 = 0, x1h1 = 0;
    if (L2on){
      int rb0 = slot2 * 16384 + b0i * 512 + uu;
      o_s0 = ld_ring_bf(out0ring, rb0);
      p_s0 = ld_ring_bf(pred0ring, rb0);
      ull xwp = __hip_atomic_load((const ull*)(xw1ring + (size_t)((slot2 * 32 + b0i) * 512 + uu) * 4),
                                  __ATOMIC_RELAXED, __HIP_MEMORY_SCOPE_AGENT);
      x1z0 = bf2f((ushort)(xwp & 0xffffu));
      x1r0 = bf2f((ushort)((xwp >> 16) & 0xffffu));
      x1h0 = bf2f((ushort)((xwp >> 32) & 0xffffu));
      if (has1){
        int rb1 = slot2 * 16384 + b1i * 512 + uu;
        o_s1 = ld_ring_bf(out0ring, rb1);
        p_s1 = ld_ring_bf(pred0ring, rb1);
        ull xwq = __hip_atomic_load((const ull*)(xw1ring + (size_t)((slot2 * 32 + b1i) * 512 + uu) * 4),
                                    __ATOMIC_RELAXED, __HIP_MEMORY_SCOPE_AGENT);
        x1z1 = bf2f((ushort)(xwq & 0xffffu));
        x1r1 = bf2f((ushort)((xwq >> 16) & 0xffffu));
        x1h1 = bf2f((ushort)((xwq >> 32) & 0xffffu));
      }
    }

    // ---- layer0 MFMA: h0[t-1] x R0 -> m_lds[0] ----
    if (L0on){
      short8 avm[16];
      if (t == 0){
        #pragma unroll
        for (int f = 0; f < 16; ++f){
          short8 v;
          #pragma unroll
          for (int j = 0; j < 8; ++j)
            v[j] = (short)f2bf(h00[f * 32 + quad * 8 + j]);
          avm[f] = v;
        }
      } else {
        const ushort* hr = h0ring + ((t - 1) & (RD - 1)) * 16384 + (mtile * 16 + lc) * 512 + quad * 8;
        #pragma unroll
        for (int f = 0; f < 16; ++f) avm[f] = ld_hc16(hr + f * 32);
      }
      f32x4 am0 = {0,0,0,0}, am1 = {0,0,0,0};
      #pragma unroll
      for (int f = 0; f < 16; ++f){
        if (f & 1) am1 = MFMA16(avm[f], bfragR0[f], am1);
        else       am0 = MFMA16(avm[f], bfragR0[f], am0);
      }
      f32x4 am = am0 + am1;
      #pragma unroll
      for (int i = 0; i < 4; ++i)
        m_lds[0][gate][(mtile << 4) + (quad << 2) + i][lc] = am[i];
    }

    // ---- layer1 MFMA: h1[tL1-1] x Rs + out0[tL1] x Ks -> m_lds[1], x_lds[0]
    if (L1on){
      short8 avm[16];
      if (t == 1){
        #pragma unroll
        for (int f = 0; f < 16; ++f){
          short8 v;
          #pragma unroll
          for (int j = 0; j < 8; ++j)
            v[j] = (short)f2bf(h01[f * 32 + quad * 8 + j]);
          avm[f] = v;
        }
      } else {
        const ushort* hr = h1ring + ((tL1 - 1) & (RD - 1)) * 16384 + (mtile * 16 + lc) * 512 + quad * 8;
        #pragma unroll
        for (int f = 0; f < 16; ++f) avm[f] = ld_hc16(hr + f * 32);
      }
      const ushort* xr_ = out0ring + slot1 * 16384 + (mtile * 16 + lc) * 512 + quad * 8;
      short8 avx[16];
      #pragma unroll
      for (int f = 0; f < 16; ++f) avx[f] = ld_hc16(xr_ + f * 32);
      f32x4 am0 = {0,0,0,0}, am1 = {0,0,0,0}, ax0 = {0,0,0,0}, ax1 = {0,0,0,0};
      #pragma unroll
      for (int f = 0; f < 16; ++f){
        short8 br = *(const short8*)(rs_lds + (((gate << 4) + f) << 9) + (lane << 3));
        short8 bk = *(const short8*)(ks_lds + (((gate << 4) + f) << 9) + (lane << 3));
        if (f & 1){ am1 = MFMA16(avm[f], br, am1); ax1 = MFMA16(avx[f], bk, ax1); }
        else      { am0 = MFMA16(avm[f], br, am0); ax0 = MFMA16(avx[f], bk, ax0); }
      }
      f32x4 am = am0 + am1, ax = ax0 + ax1;
      #pragma unroll
      for (int i = 0; i < 4; ++i){
        m_lds[1][gate][(mtile << 4) + (quad << 2) + i][lc] = am[i];
        x_lds[0][gate][(mtile << 4) + (quad << 2) + i][lc] = ax[i];
      }
    }

    // ---- layer2 MFMA: h2[tL2-1] x Rs + pred0[tL2] x Ks -> m_lds[2], x_lds[1]
    if (L2on){
      short8 avm[16];
      if (t == 2){
        #pragma unroll
        for (int f = 0; f < 16; ++f){
          short8 v;
          #pragma unroll
          for (int j = 0; j < 8; ++j)
            v[j] = (short)f2bf(h02[f * 32 + quad * 8 + j]);
          avm[f] = v;
        }
      } else {
        const ushort* hr = h2ring + ((tL2 - 1) & (RD - 1)) * 16384 + (mtile * 16 + lc) * 512 + quad * 8;
        #pragma unroll
        for (int f = 0; f < 16; ++f) avm[f] = ld_hc16(hr + f * 32);
      }
      const ushort* xr_ = pred0ring + slot2 * 16384 + (mtile * 16 + lc) * 512 + quad * 8;
      short8 avx[16];
      #pragma unroll
      for (int f = 0; f < 16; ++f) avx[f] = ld_hc16(xr_ + f * 32);
      f32x4 am0 = {0,0,0,0}, am1 = {0,0,0,0}, ax0 = {0,0,0,0}, ax1 = {0,0,0,0};
      #pragma unroll
      for (int f = 0; f < 16; ++f){
        short8 br = *(const short8*)(rs_lds + (((gate << 4) + f) << 9) + (lane << 3));
        short8 bk = *(const short8*)(ks_lds + (((gate << 4) + f) << 9) + (lane << 3));
        if (f & 1){ am1 = MFMA16(avm[f], br, am1); ax1 = MFMA16(avx[f], bk, ax1); }
        else      { am0 = MFMA16(avm[f], br, am0); ax0 = MFMA16(avx[f], bk, ax0); }
      }
      f32x4 am = am0 + am1, ax = ax0 + ax1;
      #pragma unroll
      for (int i = 0; i < 4; ++i){
        m_lds[2][gate][(mtile << 4) + (quad << 2) + i][lc] = am[i];
        x_lds[1][gate][(mtile << 4) + (quad << 2) + i][lc] = ax[i];
      }
    }
    __syncthreads();

    // ---- gate math for all live layers; ring stores (publish-early) ----
    ushort cb0 = 0, cb1 = 0;
    {
      int b = b0i;
      if (L0on){
        float mz = m_lds[0][0][b][u0] + bias_l[u0];
        float mr = m_lds[0][1][b][u0] + bias_l[16 + u0];
        float mh = m_lds[0][2][b][u0] + bias_l[32 + u0];
        float hn;
        gru_gate(mz, mr, mh, bf2f(xz0), bf2f(xr0), bf2f(xh0), hpA0, hn);
        int rb = slot0 * 16384 + b * 512 + uu;
        st_hc2(h0ring + rb, f2bf(hpA0));
        st_hc2(out0ring + rb, f2bf(hn));
      }
      if (L1on){
        float mz = m_lds[1][0][b][u0] + bias_l[48 + u0];
        float mr = m_lds[1][1][b][u0] + bias_l[64 + u0];
        float mh = m_lds[1][2][b][u0] + bias_l[80 + u0];
        float xz = x_lds[0][0][b][u0] + bias_l[96 + u0];
        float xr = x_lds[0][1][b][u0] + bias_l[112 + u0];
        float xh = x_lds[0][2][b][u0] + bias_l[128 + u0];
        float hn;
        gru_gate(mz, mr, mh, xz, xr, xh, hpA1, hn);
        int rb = slot1 * 16384 + b * 512 + uu;
        st_hc2(h1ring + rb, f2bf(hpA1));
        st_hc2(pred0ring + rb, f2bf(hn));
        ull pv = (ull)f2bf(x_lds[0][0][b][u0])
               | ((ull)f2bf(x_lds[0][1][b][u0]) << 16)
               | ((ull)f2bf(x_lds[0][2][b][u0]) << 32);
        st_hc8(xw1ring + (size_t)((slot1 * 32 + b) * 512 + uu) * 4, pv);
      }
      if (L2on){
        float mz = m_lds[2][0][b][u0] + bias_l[48 + u0];
        float mr = m_lds[2][1][b][u0] + bias_l[64 + u0];
        float mh = m_lds[2][2][b][u0] + bias_l[80 + u0];
        float xz = x1z0 + a0 * x_lds[1][0][b][u0] + bias_l[96 + u0];
        float xr = x1r0 + a0 * x_lds[1][1][b][u0] + bias_l[112 + u0];
        float xh = x1h0 + a0 * x_lds[1][2][b][u0] + bias_l[128 + u0];
        float hn;
        gru_gate(mz, mr, mh, xz, xr, xh, hpA2, hn);
        st_hc2(h2ring + slot2 * 16384 + b * 512 + uu, f2bf(hpA2));
        cb0 = f2bf(o_s0 + a1 * p_s0 + a2 * hn);
      }
    }
    if (has1){
      int b = b1i;
      if (L0on){
        float mz = m_lds[0][0][b][u0] + bias_l[u0];
        float mr = m_lds[0][1][b][u0] + bias_l[16 + u0];
        float mh = m_lds[0][2][b][u0] + bias_l[32 + u0];
        float hn;
        gru_gate(mz, mr, mh, bf2f(xz1), bf2f(xr1), bf2f(xh1), hpB0, hn);
        int rb = slot0 * 16384 + b * 512 + uu;
        st_hc2(h0ring + rb, f2bf(hpB0));
        st_hc2(out0ring + rb, f2bf(hn));
      }
      if (L1on){
        float mz = m_lds[1][0][b][u0] + bias_l[48 + u0];
        float mr = m_lds[1][1][b][u0] + bias_l[64 + u0];
        float mh = m_lds[1][2][b][u0] + bias_l[80 + u0];
        float xz = x_lds[0][0][b][u0] + bias_l[96 + u0];
        float xr = x_lds[0][1][b][u0] + bias_l[112 + u0];
        float xh = x_lds[0][2][b][u0] + bias_l[128 + u0];
        float hn;
        gru_gate(mz, mr, mh, xz, xr, xh, hpB1, hn);
        int rb = slot1 * 16384 + b * 512 + uu;
        st_hc2(h1ring + rb, f2bf(hpB1));
        st_hc2(pred0ring + rb, f2bf(hn));
        ull pv = (ull)f2bf(x_lds[0][0][b][u0])
               | ((ull)f2bf(x_lds[0][1][b][u0]) << 16)
               | ((ull)f2bf(x_lds[0][2][b][u0]) << 32);
        st_hc8(xw1ring + (size_t)((slot1 * 32 + b) * 512 + uu) * 4, pv);
      }
      if (L2on){
        float mz = m_lds[2][0][b][u0] + bias_l[48 + u0];
        float mr = m_lds[2][1][b][u0] + bias_l[64 + u0];
        float mh = m_lds[2][2][b][u0] + bias_l[80 + u0];
        float xz = x1z1 + a0 * x_lds[1][0][b][u0] + bias_l[96 + u0];
        float xr = x1r1 + a0 * x_lds[1][1][b][u0] + bias_l[112 + u0];
        float xh = x1h1 + a0 * x_lds[1][2][b][u0] + bias_l[128 + u0];
        float hn;
        gru_gate(mz, mr, mh, xz, xr, xh, hpB2, hn);
        st_hc2(h2ring + slot2 * 16384 + b * 512 + uu, f2bf(hpB2));
        cb1 = f2bf(o_s1 + a1 * p_s1 + a2 * hn);
      }
    }
    asm volatile("s_waitcnt vmcnt(0)" ::: "memory");  // ring stores at coherence pt
    __syncthreads();
    if (tid == 0)
      __hip_atomic_store(flags + t * 32 + g, 1,
                         __ATOMIC_RELAXED, __HIP_MEMORY_SCOPE_AGENT);
    // layer2 HBM output AFTER publish: off the critical path
    if (L2on){
      comb[((size_t)b0i * 1024 + tL2) * 512 + uu] = cb0;
      if (has1) comb[((size_t)b1i * 1024 + tL2) * 512 + uu] = cb1;
    }

    xz0 = nz0; xr0 = nr0; xh0 = nh0;
    xz1 = nz1; xr1 = nr1; xh1 = nh1;
  }
}

// ---------------------------------------------------------------------------
extern "C" void kernel_launch(void* const* d_in, const int* in_sizes, int n_in,
                              void* d_out, int out_size, void* d_ws, size_t ws_size,
                              hipStream_t stream)
{
  const float* x   = (const float*)d_in[0];
  const float* k0  = (const float*)d_in[1];
  const float* r0  = (const float*)d_in[2];
  const float* b0  = (const float*)d_in[3];
  const float* ks  = (const float*)d_in[4];
  const float* rs  = (const float*)d_in[5];
  const float* bs  = (const float*)d_in[6];
  const float* h00 = (const float*)d_in[7];
  const float* h01 = (const float*)d_in[8];
  const float* h02 = (const float*)d_in[9];
  const float* a   = (const float*)d_in[10];
  const float* wd  = (const float*)d_in[11];
  const float* bd  = (const float*)d_in[12];
  float* outp = (float*)d_out;

  // ws layout (bytes), ~142.8 MB total:
  //   [0,        100663296)  XW0   [32768,1536] bf16
  //   [100663296,134217728)  comb  [32768,512] bf16 (first 16.8MB aliases x_bf)
  //   [134217728,136577024)  rings (2.25 MB region; ~1.2 MB used)
  //   [136577024,136973312)  flags [FSTEPS][32] int
  //   [136973312,...]        bf16 weights k0b,r0b,ksb,rsb,wdb
  char* ws = (char*)d_ws;
  ushort* XW    = (ushort*)(ws);
  ushort* combp = (ushort*)(ws + 100663296u);
  ushort* xbf   = combp;                      // alias: dead before rec1_k runs
  ushort* rings = (ushort*)(ws + 134217728u);
  int*    flags = (int*)   (ws + 136577024u);
  ushort* k0b   = (ushort*)(ws + 136973312u);
  ushort* r0b   = (ushort*)(ws + 137759744u);
  ushort* ksb   = (ushort*)(ws + 139332608u);
  ushort* rsb   = (ushort*)(ws + 140905472u);
  ushort* wdb   = (ushort*)(ws + 142478336u);

  hipMemsetAsync(flags, 0, FSTEPS * 32 * sizeof(int), stream);

  dim3 blk(256);
  cvt_k<<<dim3(8192), blk, 0, stream>>>(x,  xbf, 8388608);
  cvt_k<<<dim3(384),  blk, 0, stream>>>(k0, k0b, 393216);
  cvt_k<<<dim3(768),  blk, 0, stream>>>(r0, r0b, 786432);
  cvt_k<<<dim3(768),  blk, 0, stream>>>(ks, ksb, 786432);
  cvt_k<<<dim3(768),  blk, 0, stream>>>(rs, rsb, 786432);
  cvt_k<<<dim3(128),  blk, 0, stream>>>(wd, wdb, 131072);

  // Layer-0 input projection (bulk GEMM)
  gemm_bias_k<0><<<dim3(512 * 24), blk, 0, stream>>>(xbf, k0b, b0, XW, 32768, 1536, 256);
  // Fused merged 3-layer recurrence (single flag plane)
  rec1_k<<<dim3(NWG), dim3(384), 0, stream>>>(XW, r0b, ksb, rsb, b0, bs,
                                              h00, h01, h02, a, combp, rings, flags);
  // Final projection: comb @ wd + bd -> fp32 d_out
  gemm_bias_k<1><<<dim3(512 * 4), blk, 0, stream>>>(combp, wdb, bd, outp, 32768, 256, 512);
}

// Round 5
// 10648.808 us; speedup vs baseline: 3.0058x; 3.0058x over previous
//
#include <hip/hip_runtime.h>

typedef __attribute__((ext_vector_type(8))) short short8;
typedef __attribute__((ext_vector_type(4))) float f32x4;
typedef __attribute__((ext_vector_type(4))) unsigned short u16x4;
typedef unsigned short ushort;
typedef unsigned long long ull;

#define MFMA16(a,b,c) __builtin_amdgcn_mfma_f32_16x16x32_bf16((a),(b),(c),0,0,0)

static __device__ __forceinline__ float bf2f(ushort u){
  union { unsigned int i; float f; } z; z.i = ((unsigned int)u) << 16; return z.f;
}
static __device__ __forceinline__ ushort f2bf(float f){
  union { float f; unsigned int i; } z; z.f = f;
  unsigned int x = z.i;
  unsigned int r = (x + 0x7fffu + ((x >> 16) & 1u)) >> 16;   // RNE
  return (ushort)r;
}

// 16B coherence-point load (2x u64 agent atomics) -- proven-correct path
static __device__ __forceinline__ short8 ld_hc16(const ushort* p){
  union { ull q[2]; short8 v; } u;
  u.q[0] = __hip_atomic_load((const ull*)p, __ATOMIC_RELAXED, __HIP_MEMORY_SCOPE_AGENT);
  u.q[1] = __hip_atomic_load((const ull*)(p + 4), __ATOMIC_RELAXED, __HIP_MEMORY_SCOPE_AGENT);
  return u.v;
}
// single bf16 from ring via aligned u32 agent atomic (proven)
static __device__ __forceinline__ float ld_ring_bf(const ushort* base, int idx){
  const unsigned int* p = (const unsigned int*)(base + (idx & ~1));
  unsigned int w = __hip_atomic_load(p, __ATOMIC_RELAXED, __HIP_MEMORY_SCOPE_AGENT);
  return bf2f((idx & 1) ? (ushort)(w >> 16) : (ushort)(w & 0xffffu));
}
// 2B / 8B write-through stores to coherence point (proven)
static __device__ __forceinline__ void st_hc2(ushort* p, ushort v){
  unsigned int vv = v;
  asm volatile("global_store_short %0, %1, off sc0 sc1" :: "v"(p), "v"(vv) : "memory");
}
static __device__ __forceinline__ void st_hc8(ushort* p, ull v){
  asm volatile("global_store_dwordx2 %0, %1, off sc0 sc1" :: "v"(p), "v"(v) : "memory");
}

// ---- batched 16-fragment system-scope load: 16 pipelined global_load_dwordx4
// from ONE base (offset:64*f) with the s_waitcnt INSIDE the asm block.
// Outputs are defined only when the block completes -> any post-block copy or
// spill is benign (fixes round-4's issue/wait split hazard). All 16 loads are
// in flight simultaneously: 1 L3 round-trip instead of 16 serialized.
static __device__ __forceinline__ void ld_frag16(const ushort* p, short8* o){
  asm volatile(
    "global_load_dwordx4 %0, %16, off sc0 sc1\n\t"
    "global_load_dwordx4 %1, %16, off offset:64 sc0 sc1\n\t"
    "global_load_dwordx4 %2, %16, off offset:128 sc0 sc1\n\t"
    "global_load_dwordx4 %3, %16, off offset:192 sc0 sc1\n\t"
    "global_load_dwordx4 %4, %16, off offset:256 sc0 sc1\n\t"
    "global_load_dwordx4 %5, %16, off offset:320 sc0 sc1\n\t"
    "global_load_dwordx4 %6, %16, off offset:384 sc0 sc1\n\t"
    "global_load_dwordx4 %7, %16, off offset:448 sc0 sc1\n\t"
    "global_load_dwordx4 %8, %16, off offset:512 sc0 sc1\n\t"
    "global_load_dwordx4 %9, %16, off offset:576 sc0 sc1\n\t"
    "global_load_dwordx4 %10, %16, off offset:640 sc0 sc1\n\t"
    "global_load_dwordx4 %11, %16, off offset:704 sc0 sc1\n\t"
    "global_load_dwordx4 %12, %16, off offset:768 sc0 sc1\n\t"
    "global_load_dwordx4 %13, %16, off offset:832 sc0 sc1\n\t"
    "global_load_dwordx4 %14, %16, off offset:896 sc0 sc1\n\t"
    "global_load_dwordx4 %15, %16, off offset:960 sc0 sc1\n\t"
    "s_waitcnt vmcnt(0)"
    : "=&v"(o[0]), "=&v"(o[1]), "=&v"(o[2]), "=&v"(o[3]),
      "=&v"(o[4]), "=&v"(o[5]), "=&v"(o[6]), "=&v"(o[7]),
      "=&v"(o[8]), "=&v"(o[9]), "=&v"(o[10]), "=&v"(o[11]),
      "=&v"(o[12]), "=&v"(o[13]), "=&v"(o[14]), "=&v"(o[15])
    : "v"(p)
    : "memory");
  __builtin_amdgcn_sched_barrier(0);
}

// ---------------------------------------------------------------------------
// fp32 -> bf16 convert, 4 elems/thread
// ---------------------------------------------------------------------------
__global__ __launch_bounds__(256) void cvt_k(
    const float* __restrict__ in, ushort* __restrict__ out, int n)
{
  int i = (blockIdx.x * 256 + threadIdx.x) * 4;
  if (i < n){
    float4 v = *(const float4*)(in + i);
    u16x4 o = { f2bf(v.x), f2bf(v.y), f2bf(v.z), f2bf(v.w) };
    *(u16x4*)(out + i) = o;
  }
}

// ---------------------------------------------------------------------------
// GEMM: C[M,N] = A[M,K](bf16) @ B[K,N](bf16) + bias[N](fp32).
// ---------------------------------------------------------------------------
template<int F32OUT>
__global__ __launch_bounds__(256) void gemm_bias_k(
    const ushort* __restrict__ A,
    const ushort* __restrict__ B,
    const float*  __restrict__ bias,
    void* __restrict__ Cv,
    int M, int N, int K)
{
  __shared__ __align__(16) ushort Blds[64 * 40];
  const int tid  = threadIdx.x;
  const int wid  = tid >> 6;
  const int lane = tid & 63;
  const int quad = lane >> 4;
  const int lc   = lane & 15;
  const int nb   = N >> 6;
  const int bn   = (blockIdx.x % nb) << 6;
  const int bm   = (blockIdx.x / nb) << 6;

  const int sk  = tid >> 3;
  const int scg = tid & 7;

  f32x4 acc[4] = {{0,0,0,0},{0,0,0,0},{0,0,0,0},{0,0,0,0}};
  const int arow = bm + wid * 16 + lc;
  const ushort* aptr = A + (size_t)arow * K + quad * 8;

  for (int k0 = 0; k0 < K; k0 += 32){
    short8 bv = *(const short8*)(B + (size_t)(k0 + sk) * N + bn + (scg << 3));
    #pragma unroll
    for (int i = 0; i < 8; ++i){
      int c = (scg << 3) + i;
      int p = c * 40 + (((sk >> 3) ^ (scg & 3)) << 3) + (sk & 7);
      Blds[p] = (ushort)bv[i];
    }
    __syncthreads();
    short8 av = *(const short8*)(aptr + k0);
    #pragma unroll
    for (int nt = 0; nt < 4; ++nt){
      int c2 = (nt << 4) + lc;
      int p  = c2 * 40 + ((quad ^ ((c2 >> 3) & 3)) << 3);
      short8 bfrag = *(const short8*)(Blds + p);
      acc[nt] = MFMA16(av, bfrag, acc[nt]);
    }
    __syncthreads();
  }
  #pragma unroll
  for (int nt = 0; nt < 4; ++nt){
    #pragma unroll
    for (int i = 0; i < 4; ++i){
      int m = bm + wid * 16 + quad * 4 + i;
      int n = bn + (nt << 4) + lc;
      float v = acc[nt][i] + bias[n];
      if (F32OUT) ((float*)Cv)[(size_t)m * N + n] = v;
      else        ((ushort*)Cv)[(size_t)m * N + n] = f2bf(v);
    }
  }
}

// ---------------------------------------------------------------------------
// Fused 3-layer pipelined GRU recurrence, DE-LOCKSTEPPED. 96 WGs x 384 thr.
// Protocol identical to the proven 14.8ms kernel. Only change: ring fragment
// loads use ld_frag16 (batched, wait-inside-asm) instead of per-fragment
// atomic loads -> 2 L3 round-trips per step instead of up to 32 serialized.
// ---------------------------------------------------------------------------
#define NWG 96
#define RD 8
#define FSTEPS 1032

__global__ __launch_bounds__(384, 1) void rec3_k(
    const ushort* __restrict__ xw0,   // [32*1024,1536] bf16, row = b*1024+t
    const ushort* __restrict__ R0b,   // [512,1536]
    const ushort* __restrict__ Ksb,   // [512,1536]
    const ushort* __restrict__ Rsb,   // [512,1536]
    const float*  __restrict__ b0v,   // [2,1536]
    const float*  __restrict__ bsv,   // [2,1536]
    const float*  __restrict__ h00,
    const float*  __restrict__ h01,
    const float*  __restrict__ h02,
    const float*  __restrict__ av,    // [3]
    ushort* __restrict__ comb,        // [32*1024,512] bf16
    ushort* __restrict__ rings,
    int* __restrict__ flags)          // [3][FSTEPS][32]
{
  __shared__ float m_lds[3][32][17];
  __shared__ float x_lds[3][32][17];
  __shared__ float bias_l[96];                       // [0:48) b_rec, [48:96) b_in(bs)
  __shared__ __align__(16) ushort ks_lds[3 * 16 * 64 * 8];  // 48 KB

  const int tid  = threadIdx.x;
  const int wid  = tid >> 6;
  const int lane = tid & 63;
  const int quad = lane >> 4;
  const int lc   = lane & 15;
  const int bid  = blockIdx.x;
  const int role = bid >> 5;
  const int g    = bid & 31;
  const int ug0  = g << 4;
  const int gate = wid % 3, mtile = wid / 3;
  const int col0 = (gate << 9) + ug0;

  // ring layout (ushort units): h[3] 131072 each; out0 131072; pred0 131072;
  // xw1 [8][32][512][4] = 524288
  ushort* h_ring    = rings + role * 131072;
  ushort* out0ring  = rings + 393216;
  ushort* pred0ring = rings + 524288;
  ushort* xw1ring   = rings + 655360;

  // ---- recurrent-weight fragments in VGPRs ----
  const ushort* Rw = (role == 0) ? R0b : Rsb;
  short8 bfragR[16];
  #pragma unroll
  for (int f = 0; f < 16; ++f){
    short8 v;
    #pragma unroll
    for (int j = 0; j < 8; ++j)
      v[j] = (short)Rw[(size_t)(f * 32 + quad * 8 + j) * 1536 + col0 + lc];
    bfragR[f] = v;
  }
  // ---- Ks slice into LDS (roles 1,2), one wave per gate ----
  if (role > 0 && mtile == 0){
    #pragma unroll
    for (int f = 0; f < 16; ++f){
      short8 v;
      #pragma unroll
      for (int j = 0; j < 8; ++j)
        v[j] = (short)Ksb[(size_t)(f * 32 + quad * 8 + j) * 1536 + col0 + lc];
      *(short8*)(ks_lds + (((gate << 4) + f) << 9) + (lane << 3)) = v;
    }
  }
  const float* brec = ((role == 0) ? b0v : bsv) + 1536;
  if (tid < 48) bias_l[tid] = brec[(tid >> 4) * 512 + ug0 + (tid & 15)];
  if (tid >= 48 && tid < 96) bias_l[tid] = bsv[((tid - 48) >> 4) * 512 + ug0 + ((tid - 48) & 15)];
  const float a0 = av[0], a1 = av[1], a2 = av[2];
  const float* hinit = (role == 0) ? h00 : (role == 1) ? h01 : h02;

  const int  b0i  = tid >> 4;
  const int  u0   = tid & 15;
  const int  b1i  = (tid + 384) >> 4;
  const bool has1 = (tid < 128);
  const int  uu   = ug0 + u0;
  float hp0 = hinit[uu];
  float hp1 = hp0;

  // ---- role0 xw prefetch for t=0 ----
  ushort xz0 = 0, xr0 = 0, xh0 = 0, xz1 = 0, xr1 = 0, xh1 = 0;
  if (role == 0){
    size_t r0_ = ((size_t)b0i * 1024) * 1536 + uu;
    xz0 = xw0[r0_]; xr0 = xw0[r0_ + 512]; xh0 = xw0[r0_ + 1024];
    if (has1){
      size_t r1_ = ((size_t)b1i * 1024) * 1536 + uu;
      xz1 = xw0[r1_]; xr1 = xw0[r1_ + 512]; xh1 = xw0[r1_ + 1024];
    }
  }
  __syncthreads();

  long budget = 40000000L;  // spin safety valve: degrade, don't hang
  for (int t = 0; t < 1024; ++t){
    const int s     = t + role;
    const int slot  = t & (RD - 1);
    const int pslot = (t - 1) & (RD - 1);

    // role0: prefetch next xw (independent of flags)
    ushort nz0 = 0, nr0 = 0, nh0 = 0, nz1 = 0, nr1 = 0, nh1 = 0;
    if (role == 0 && t < 1023){
      size_t r0_ = ((size_t)b0i * 1024 + t + 1) * 1536 + uu;
      nz0 = xw0[r0_]; nr0 = xw0[r0_ + 512]; nh0 = xw0[r0_ + 1024];
      if (has1){
        size_t r1_ = ((size_t)b1i * 1024 + t + 1) * 1536 + uu;
        nz1 = xw0[r1_]; nr1 = xw0[r1_ + 512]; nh1 = xw0[r1_ + 1024];
      }
    }

    // ---- de-lockstepped wait (unchanged from proven kernel) ----
    {
      const bool needO = (t > 0);                       // own h ring
      const bool needP = (role >= 1);                   // prev-role stream
      const bool needF = (role <= 1) && (s >= RD);      // ring back-pressure
      if ((needO || needP || needF) && wid == 0){
        const int  l    = lane & 31;
        const int* fo   = flags + (role * FSTEPS + (s - 1)) * 32 + l;
        const int* fp   = flags + ((role - 1) * FSTEPS + (s - 1)) * 32 + l;
        const int* ff   = flags + (2 * FSTEPS + (s - 6)) * 32 + l;
        while (budget > 0){
          bool ok = true;
          if (needO) ok &= (__hip_atomic_load(fo, __ATOMIC_RELAXED, __HIP_MEMORY_SCOPE_AGENT) != 0);
          if (needP) ok &= (__hip_atomic_load(fp, __ATOMIC_RELAXED, __HIP_MEMORY_SCOPE_AGENT) != 0);
          if (needF) ok &= (__hip_atomic_load(ff, __ATOMIC_RELAXED, __HIP_MEMORY_SCOPE_AGENT) != 0);
          if (__ballot(ok) == ~0ull) break;
          --budget;
        }
      }
      __syncthreads();
    }

    // role2: scalar ring loads (issued first; drained by first ld_frag16)
    float o_s0 = 0, p_s0 = 0, x1z0 = 0, x1r0 = 0, x1h0 = 0;
    float o_s1 = 0, p_s1 = 0, x1z1 = 0, x1r1 = 0, x1h1 = 0;
    if (role == 2){
      int rb0 = slot * 16384 + b0i * 512 + uu;
      o_s0 = ld_ring_bf(out0ring, rb0);
      p_s0 = ld_ring_bf(pred0ring, rb0);
      ull xwp = __hip_atomic_load((const ull*)(xw1ring + (size_t)((slot * 32 + b0i) * 512 + uu) * 4),
                                  __ATOMIC_RELAXED, __HIP_MEMORY_SCOPE_AGENT);
      x1z0 = bf2f((ushort)(xwp & 0xffffu));
      x1r0 = bf2f((ushort)((xwp >> 16) & 0xffffu));
      x1h0 = bf2f((ushort)((xwp >> 32) & 0xffffu));
      if (has1){
        int rb1 = slot * 16384 + b1i * 512 + uu;
        o_s1 = ld_ring_bf(out0ring, rb1);
        p_s1 = ld_ring_bf(pred0ring, rb1);
        ull xwq = __hip_atomic_load((const ull*)(xw1ring + (size_t)((slot * 32 + b1i) * 512 + uu) * 4),
                                    __ATOMIC_RELAXED, __HIP_MEMORY_SCOPE_AGENT);
        x1z1 = bf2f((ushort)(xwq & 0xffffu));
        x1r1 = bf2f((ushort)((xwq >> 16) & 0xffffu));
        x1h1 = bf2f((ushort)((xwq >> 32) & 0xffffu));
      }
    }

    // ---- A-frags (batched) + recurrent (and input) MFMA ----
    {
      short8 avm[16];
      short8 avx[16];
      if (role >= 1){
        const ushort* xr_ = ((role == 1) ? out0ring : pred0ring)
                          + slot * 16384 + (mtile * 16 + lc) * 512 + quad * 8;
        ld_frag16(xr_, avx);            // 1 pipelined round-trip (+ scalars)
      }
      if (t == 0){
        #pragma unroll
        for (int f = 0; f < 16; ++f){
          short8 v;
          #pragma unroll
          for (int j = 0; j < 8; ++j)
            v[j] = (short)f2bf(hinit[f * 32 + quad * 8 + j]);
          avm[f] = v;
        }
      } else {
        const ushort* hr = h_ring + pslot * 16384 + (mtile * 16 + lc) * 512 + quad * 8;
        ld_frag16(hr, avm);             // 1 pipelined round-trip
      }

      f32x4 am0 = {0,0,0,0}, am1 = {0,0,0,0};
      if (role == 0){
        #pragma unroll
        for (int f = 0; f < 16; ++f){
          if (f & 1) am1 = MFMA16(avm[f], bfragR[f], am1);
          else       am0 = MFMA16(avm[f], bfragR[f], am0);
        }
        f32x4 am = am0 + am1;
        #pragma unroll
        for (int i = 0; i < 4; ++i)
          m_lds[gate][(mtile << 4) + (quad << 2) + i][lc] = am[i];
      } else {
        f32x4 ax0 = {0,0,0,0}, ax1 = {0,0,0,0};
        #pragma unroll
        for (int f = 0; f < 16; ++f){
          short8 bx = *(const short8*)(ks_lds + (((gate << 4) + f) << 9) + (lane << 3));
          if (f & 1){ am1 = MFMA16(avm[f], bfragR[f], am1); ax1 = MFMA16(avx[f], bx, ax1); }
          else      { am0 = MFMA16(avm[f], bfragR[f], am0); ax0 = MFMA16(avx[f], bx, ax0); }
        }
        f32x4 am = am0 + am1, ax = ax0 + ax1;
        #pragma unroll
        for (int i = 0; i < 4; ++i){
          m_lds[gate][(mtile << 4) + (quad << 2) + i][lc] = am[i];
          x_lds[gate][(mtile << 4) + (quad << 2) + i][lc] = ax[i];
        }
      }
    }
    __syncthreads();

    // ---- gate math; ring stores only (publish-early) ----
    ushort cb0 = 0, cb1 = 0;
    {
      int b = b0i;
      float mz = m_lds[0][b][u0] + bias_l[u0];
      float mr = m_lds[1][b][u0] + bias_l[16 + u0];
      float mh = m_lds[2][b][u0] + bias_l[32 + u0];
      float xz, xr, xh;
      if (role == 0){ xz = bf2f(xz0); xr = bf2f(xr0); xh = bf2f(xh0); }
      else if (role == 1){
        xz = x_lds[0][b][u0] + bias_l[48 + u0];
        xr = x_lds[1][b][u0] + bias_l[64 + u0];
        xh = x_lds[2][b][u0] + bias_l[80 + u0];
      } else {
        xz = x1z0 + a0 * x_lds[0][b][u0] + bias_l[48 + u0];
        xr = x1r0 + a0 * x_lds[1][b][u0] + bias_l[64 + u0];
        xh = x1h0 + a0 * x_lds[2][b][u0] + bias_l[80 + u0];
      }
      float z  = 1.f / (1.f + __expf(-(xz + mz)));
      float r  = 1.f / (1.f + __expf(-(xr + mr)));
      float axv = xh + r * mh;
      float hh = 1.f - 2.f / (1.f + __expf(2.f * axv));
      float hn = z * hp0 + (1.f - z) * hh;
      float hcv = hn + 0.1f * (hp0 - hn);
      hp0 = hcv;
      int rb = slot * 16384 + b * 512 + uu;
      st_hc2(h_ring + rb, f2bf(hcv));
      if (role == 0) st_hc2(out0ring + rb, f2bf(hn));
      else if (role == 1){
        st_hc2(pred0ring + rb, f2bf(hn));
        ull pv = (ull)f2bf(x_lds[0][b][u0])
               | ((ull)f2bf(x_lds[1][b][u0]) << 16)
               | ((ull)f2bf(x_lds[2][b][u0]) << 32);
        st_hc8(xw1ring + (size_t)((slot * 32 + b) * 512 + uu) * 4, pv);
      } else {
        cb0 = f2bf(o_s0 + a1 * p_s0 + a2 * hn);
      }
    }
    if (has1){
      int b = b1i;
      float mz = m_lds[0][b][u0] + bias_l[u0];
      float mr = m_lds[1][b][u0] + bias_l[16 + u0];
      float mh = m_lds[2][b][u0] + bias_l[32 + u0];
      float xz, xr, xh;
      if (role == 0){ xz = bf2f(xz1); xr = bf2f(xr1); xh = bf2f(xh1); }
      else if (role == 1){
        xz = x_lds[0][b][u0] + bias_l[48 + u0];
        xr = x_lds[1][b][u0] + bias_l[64 + u0];
        xh = x_lds[2][b][u0] + bias_l[80 + u0];
      } else {
        xz = x1z1 + a0 * x_lds[0][b][u0] + bias_l[48 + u0];
        xr = x1r1 + a0 * x_lds[1][b][u0] + bias_l[64 + u0];
        xh = x1h1 + a0 * x_lds[2][b][u0] + bias_l[80 + u0];
      }
      float z  = 1.f / (1.f + __expf(-(xz + mz)));
      float r  = 1.f / (1.f + __expf(-(xr + mr)));
      float axv = xh + r * mh;
      float hh = 1.f - 2.f / (1.f + __expf(2.f * axv));
      float hn = z * hp1 + (1.f - z) * hh;
      float hcv = hn + 0.1f * (hp1 - hn);
      hp1 = hcv;
      int rb = slot * 16384 + b * 512 + uu;
      st_hc2(h_ring + rb, f2bf(hcv));
      if (role == 0) st_hc2(out0ring + rb, f2bf(hn));
      else if (role == 1){
        st_hc2(pred0ring + rb, f2bf(hn));
        ull pv = (ull)f2bf(x_lds[0][b][u0])
               | ((ull)f2bf(x_lds[1][b][u0]) << 16)
               | ((ull)f2bf(x_lds[2][b][u0]) << 32);
        st_hc8(xw1ring + (size_t)((slot * 32 + b) * 512 + uu) * 4, pv);
      } else {
        cb1 = f2bf(o_s1 + a1 * p_s1 + a2 * hn);
      }
    }
    asm volatile("s_waitcnt vmcnt(0)" ::: "memory");  // ring stores at coherence pt
    __syncthreads();
    if (tid == 0)
      __hip_atomic_store(flags + (role * FSTEPS + s) * 32 + g, 1,
                         __ATOMIC_RELAXED, __HIP_MEMORY_SCOPE_AGENT);
    // role2 HBM output AFTER publish: off the critical path
    if (role == 2){
      comb[((size_t)b0i * 1024 + t) * 512 + uu] = cb0;
      if (has1) comb[((size_t)b1i * 1024 + t) * 512 + uu] = cb1;
    }

    if (role == 0){
      xz0 = nz0; xr0 = nr0; xh0 = nh0;
      xz1 = nz1; xr1 = nr1; xh1 = nh1;
    }
  }
}

// ---------------------------------------------------------------------------
extern "C" void kernel_launch(void* const* d_in, const int* in_sizes, int n_in,
                              void* d_out, int out_size, void* d_ws, size_t ws_size,
                              hipStream_t stream)
{
  const float* x   = (const float*)d_in[0];
  const float* k0  = (const float*)d_in[1];
  const float* r0  = (const float*)d_in[2];
  const float* b0  = (const float*)d_in[3];
  const float* ks  = (const float*)d_in[4];
  const float* rs  = (const float*)d_in[5];
  const float* bs  = (const float*)d_in[6];
  const float* h00 = (const float*)d_in[7];
  const float* h01 = (const float*)d_in[8];
  const float* h02 = (const float*)d_in[9];
  const float* a   = (const float*)d_in[10];
  const float* wd  = (const float*)d_in[11];
  const float* bd  = (const float*)d_in[12];
  float* outp = (float*)d_out;

  // ws layout (bytes), ~142.8 MB total:
  //   [0,        100663296)  XW0   [32768,1536] bf16
  //   [100663296,134217728)  comb  [32768,512] bf16 (first 16.8MB aliases x_bf)
  //   [134217728,136577024)  rings (2.25 MB)
  //   [136577024,136973312)  flags [3][1032][32] int
  //   [136973312,...]        bf16 weights k0b,r0b,ksb,rsb,wdb
  char* ws = (char*)d_ws;
  ushort* XW    = (ushort*)(ws);
  ushort* combp = (ushort*)(ws + 100663296u);
  ushort* xbf   = combp;                      // alias: dead before rec3_k runs
  ushort* rings = (ushort*)(ws + 134217728u);
  int*    flags = (int*)   (ws + 136577024u);
  ushort* k0b   = (ushort*)(ws + 136973312u);
  ushort* r0b   = (ushort*)(ws + 137759744u);
  ushort* ksb   = (ushort*)(ws + 139332608u);
  ushort* rsb   = (ushort*)(ws + 140905472u);
  ushort* wdb   = (ushort*)(ws + 142478336u);

  hipMemsetAsync(flags, 0, 3 * FSTEPS * 32 * sizeof(int), stream);

  dim3 blk(256);
  cvt_k<<<dim3(8192), blk, 0, stream>>>(x,  xbf, 8388608);
  cvt_k<<<dim3(384),  blk, 0, stream>>>(k0, k0b, 393216);
  cvt_k<<<dim3(768),  blk, 0, stream>>>(r0, r0b, 786432);
  cvt_k<<<dim3(768),  blk, 0, stream>>>(ks, ksb, 786432);
  cvt_k<<<dim3(768),  blk, 0, stream>>>(rs, rsb, 786432);
  cvt_k<<<dim3(128),  blk, 0, stream>>>(wd, wdb, 131072);

  // Layer-0 input projection (bulk GEMM)
  gemm_bias_k<0><<<dim3(512 * 24), blk, 0, stream>>>(xbf, k0b, b0, XW, 32768, 1536, 256);
  // Fused pipelined 3-layer recurrence (de-lockstepped, batched ring loads)
  rec3_k<<<dim3(NWG), dim3(384), 0, stream>>>(XW, r0b, ksb, rsb, b0, bs,
                                              h00, h01, h02, a, combp, rings, flags);
  // Final projection: comb @ wd + bd -> fp32 d_out
  gemm_bias_k<1><<<dim3(512 * 4), blk, 0, stream>>>(combp, wdb, bd, outp, 32768, 256, 512);
}